// Round 9
// baseline (93.607 us; speedup 1.0000x reference)
//
#include <hip/hip_runtime.h>

#define WW   48
#define NPIX 2304
#define CIN  32
#define COUT 64
#define KNB  29
#define FCO  16
#define NPJ  (NPIX * KNB)        // 66816 (p,j) pairs

// workspace layout (bytes); total 8,534,080
#define WS_RP64 0                // 2304*9*8    = 165888   f64 Rp
#define WS_EG   165888           // 2304*6*16*4 = 884736   edge MLP outs
#define WS_M0   1050624          // 16*4        = 64       MLP(0)
#define WS_V    1050688          // 66816*12*4  = 3207168  v_d logs (f32)
#define WS_PART 4257856          // 66816*16*4  = 4276224  per-(p,j) 9-eval sums

typedef float v2f __attribute__((ext_vector_type(2)));

__device__ __forceinline__ float swish_f(float x) {
    return x * __builtin_amdgcn_rcpf(1.0f + __expf(-x));
}

// f64 Rodrigues matching reference so3_exp
__device__ __forceinline__ void so3_exp_d(double wx, double wy, double wz, double R[9]) {
    double n  = sqrt(wx * wx + wy * wy + wz * wz);
    double th = fmax(n, 1e-7);
    double kx = wx / th, ky = wy / th, kz = wz / th;
    double s = sin(th), c = cos(th);
    double omc = 1.0 - c;
    R[0] = 1.0 + omc * (kx * kx - 1.0);
    R[1] = -s * kz + omc * kx * ky;
    R[2] =  s * ky + omc * kx * kz;
    R[3] =  s * kz + omc * kx * ky;
    R[4] = 1.0 + omc * (ky * ky - 1.0);
    R[5] = -s * kx + omc * ky * kz;
    R[6] = -s * ky + omc * kz * kx;
    R[7] =  s * kx + omc * kz * ky;
    R[8] = 1.0 + omc * (kz * kz - 1.0);
}

// f64 fisheye lift rotation Rp for pixel p (matches reference _lift_log)
__device__ __forceinline__ void compute_Rp_d(int p, double R[9]) {
    int ui = p % WW, vi = p / WW;
    double dx = (double)ui - 23.5;
    double dy = (double)vi - 23.5;
    double r  = sqrt(dx * dx + dy * dy);
    const double FOCAL = 48.0 / 3.14159265358979323846;
    double theta = r / FOCAL;
    double rs = fmax(r, 1e-7);
    double st = sin(theta);
    double rayx = st * dx / rs;
    double rayy = st * dy / rs;
    double rayz = cos(theta);
    double pz  = fmin(fmax(rayz, -1.0 + 1e-6), 1.0 - 1e-6);
    double ang = acos(pz);
    double ax = -rayy, ay = rayx;
    double an = fmax(sqrt(ax * ax + ay * ay), 1e-7);
    ax /= an; ay /= an;
    so3_exp_d(ax * ang, ay * ang, 0.0, R);
}

// One 16-column half of layer2 + its layer3 fold, in float2-PAIR form:
// accumulator pairs (q,q+1) / (f,f+1) are v2f; weight pairs are consecutive
// in memory (uniform -> s_load_dwordx2, 64-bit scalar operand of v_pk_fma_f32);
// h is splatted once per i (32 splats vs 512 FMAs).
// Summation order per accumulator element identical to scalar version.
__device__ __forceinline__ void mlp_half(float ab0, float ab1, float ab2, const int Q0,
    const float* __restrict__ W1, const float* __restrict__ b1,
    const float* __restrict__ W2, const float* __restrict__ b2,
    const float* __restrict__ W3, const float* __restrict__ b3,
    v2f* acc3p) {
    v2f accq[8];
    #pragma unroll
    for (int q8 = 0; q8 < 8; ++q8)
        accq[q8] = *(const v2f*)&b2[Q0 + 2 * q8];
    #pragma unroll
    for (int i = 0; i < 32; ++i) {
        float h = swish_f(b1[i] + ab0 * W1[i] + ab1 * W1[32 + i] + ab2 * W1[64 + i]);
        v2f hh = {h, h};
        #pragma unroll
        for (int q8 = 0; q8 < 8; ++q8)
            accq[q8] += hh * (*(const v2f*)&W2[i * 32 + Q0 + 2 * q8]);
    }
    #pragma unroll
    for (int q = 0; q < 16; ++q) {
        float h2 = swish_f(accq[q >> 1][q & 1]);
        v2f hh2 = {h2, h2};
        const float* w3r = &W3[(Q0 + q) * FCO];
        #pragma unroll
        for (int f8 = 0; f8 < 8; ++f8)
            acc3p[f8] += hh2 * (*(const v2f*)&w3r[2 * f8]);
    }
}

// streaming f32 MLP 3->32->32->16 in two low-pressure passes
__device__ __forceinline__ void mlp_eval(float ab0, float ab1, float ab2,
    const float* __restrict__ W1, const float* __restrict__ b1,
    const float* __restrict__ W2, const float* __restrict__ b2,
    const float* __restrict__ W3, const float* __restrict__ b3,
    float* o) {
    v2f acc3p[8];
    #pragma unroll
    for (int f8 = 0; f8 < 8; ++f8)
        acc3p[f8] = *(const v2f*)&b3[2 * f8];
    mlp_half(ab0, ab1, ab2, 0,  W1, b1, W2, b2, W3, b3, acc3p);
    __builtin_amdgcn_sched_barrier(0);   // keep the two passes' pressure isolated
    mlp_half(ab0, ab1, ab2, 16, W1, b1, W2, b2, W3, b3, acc3p);
    #pragma unroll
    for (int f = 0; f < FCO; ++f) o[f] = swish_f(acc3p[f >> 1][f & 1]);
}

// ---------------- K0: per-pixel f64 lift rotation ----------------
__global__ __launch_bounds__(256)
void rp_kernel(double* __restrict__ rp64) {
    int p = blockIdx.x * 256 + threadIdx.x;
    if (p >= NPIX) return;
    double R[9];
    compute_Rp_d(p, R);
    #pragma unroll
    for (int e = 0; e < 9; ++e) rp64[p * 9 + e] = R[e];
}

// ---------------- K1: per-pixel edge MLP evals ----------------
__global__ __launch_bounds__(256)
void edge_kernel(const float* __restrict__ W1, const float* __restrict__ b1,
                 const float* __restrict__ W2, const float* __restrict__ b2,
                 const float* __restrict__ W3, const float* __restrict__ b3,
                 const double* __restrict__ rp64, float* __restrict__ eg,
                 float* __restrict__ m0v) {
    int g = blockIdx.x * 256 + threadIdx.x;
    if (g > NPIX * 6) return;
    if (g == NPIX * 6) {
        float o[FCO];
        mlp_eval(0.f, 0.f, 0.f, W1, b1, W2, b2, W3, b3, o);
        #pragma unroll
        for (int f = 0; f < FCO; ++f) m0v[f] = o[f];
        return;
    }
    int pix = g / 6, which = g - pix * 6;
    double R[9];
    #pragma unroll
    for (int e = 0; e < 9; ++e) R[e] = rp64[pix * 9 + e];
    int m = (which < 3) ? which : (which - 3);
    int l = m + (m >> 1);                       // 0,1,3
    double c = (l == 0) ? 1.0 : 0.0;
    double s = (l == 1) ? 1.0 : ((l == 3) ? -1.0 : 0.0);
    double M[9];
    #pragma unroll
    for (int i = 0; i < 3; ++i) {
        M[i * 3 + 0] =  R[i * 3 + 0] * c + R[i * 3 + 1] * s;
        M[i * 3 + 1] = -R[i * 3 + 0] * s + R[i * 3 + 1] * c;
        M[i * 3 + 2] =  R[i * 3 + 2];
    }
    double tr   = M[0] + M[4] + M[8];
    double cosv = fmin(fmax((tr - 1.0) * 0.5, -1.0 + 1e-6), 1.0 - 1e-6);
    double th   = acos(cosv);
    double sv   = sqrt((1.0 - cosv) * (1.0 + cosv));
    double fac  = th / (2.0 * sv);
    float sg = (which < 3) ? 1.f : -1.f;
    float o[FCO];
    mlp_eval(sg * (float)((M[7] - M[5]) * fac),
             sg * (float)((M[2] - M[6]) * fac),
             sg * (float)((M[3] - M[1]) * fac),
             W1, b1, W2, b2, W3, b3, o);
    #pragma unroll
    for (int f = 0; f < FCO; ++f) eg[g * FCO + f] = o[f];
}

// ---------------- K2: per-(p,j) relative rotation + 4 logs ----------------
__global__ __launch_bounds__(256)
void vlog_kernel(const int* __restrict__ nbr, const double* __restrict__ rp64,
                 float* __restrict__ vws) {
    int tid = blockIdx.x * 256 + threadIdx.x;
    if (tid >= NPJ) return;
    int p = tid / KNB, j = tid - p * KNB;
    int idx = nbr[p * KNB + j];
    int pj = max(idx, 0);
    double Rq[9], Rn[9];
    #pragma unroll
    for (int e = 0; e < 9; ++e) Rq[e] = rp64[p * 9 + e];
    #pragma unroll
    for (int e = 0; e < 9; ++e) Rn[e] = rp64[pj * 9 + e];
    double X[9];
    #pragma unroll
    for (int i = 0; i < 3; ++i)
        #pragma unroll
        for (int jj = 0; jj < 3; ++jj) {
            double acc = 0.0;
            #pragma unroll
            for (int kk = 0; kk < 3; ++kk)
                acc += Rn[kk * 3 + i] * Rq[kk * 3 + jj];
            X[i * 3 + jj] = acc;
        }
    float* dst = vws + tid * 12;
    #pragma unroll
    for (int d = 0; d < 4; ++d) {
        double c = (d == 0) ? 1.0 : ((d == 2) ? -1.0 : 0.0);
        double s = (d == 1) ? 1.0 : ((d == 3) ? -1.0 : 0.0);
        double M0 =  X[0] * c + X[1] * s;
        double M1 = -X[0] * s + X[1] * c;
        double M2 =  X[2];
        double M3 =  X[3] * c + X[4] * s;
        double M4 = -X[3] * s + X[4] * c;
        double M5 =  X[5];
        double M6 =  X[6] * c + X[7] * s;
        double M7 = -X[6] * s + X[7] * c;
        double M8 =  X[8];
        double tr   = M0 + M4 + M8;
        double cosv = fmin(fmax((tr - 1.0) * 0.5, -1.0 + 1e-6), 1.0 - 1e-6);
        double th   = acos(cosv);
        double svv  = sqrt((1.0 - cosv) * (1.0 + cosv));
        double fac  = th / (2.0 * svv);
        dst[d * 3 + 0] = (float)((M7 - M5) * fac);
        dst[d * 3 + 1] = (float)((M2 - M6) * fac);
        dst[d * 3 + 2] = (float)((M3 - M1) * fac);
    }
}

// ---------------- K3: ONE generic MLP eval per thread ----------------
// Wave layout: 7 (p,j) pairs per wave, 9 lanes each (lane 63 idle).
__global__ __launch_bounds__(256)
void mlp1_kernel(const float* __restrict__ W1, const float* __restrict__ b1,
                 const float* __restrict__ W2, const float* __restrict__ b2,
                 const float* __restrict__ W3, const float* __restrict__ b3,
                 const float* __restrict__ vws, float* __restrict__ part) {
    int wave = blockIdx.x * 4 + (threadIdx.x >> 6);
    int lane = threadIdx.x & 63;
    int slot = lane / 9;              // 0..7
    int e    = lane - slot * 9;       // 0..8
    int g2   = wave * 7 + slot;
    int g2c  = min(g2, NPJ - 1);
    int l1m = e / 3, l2m = e - l1m * 3;
    int l1 = l1m + (l1m >> 1);        // 0,1,3
    int l2 = l2m + (l2m >> 1);
    int d  = (l1 - l2) & 3;
    const float* vp = vws + g2c * 12 + d * 3;
    float v0 = vp[0], v1 = vp[1], v2 = vp[2];
    float ab0 = (l2m == 0) ? v0 : ((l2m == 1) ?  v1 : -v1);
    float ab1 = (l2m == 0) ? v1 : ((l2m == 1) ? -v0 :  v0);
    float o[FCO];
    mlp_eval(ab0, ab1, v2, W1, b1, W2, b2, W3, b3, o);
    // 9-lane reduction: offsets (1,2) then (3,6)
    #pragma unroll
    for (int f = 0; f < FCO; ++f) {
        float a = o[f];
        a += __shfl(a, min(lane + 1, 63)) + __shfl(a, min(lane + 2, 63));
        a += __shfl(a, min(lane + 3, 63)) + __shfl(a, min(lane + 6, 63));
        o[f] = a;
    }
    if (e == 0 && lane < 63 && g2 < NPJ) {
        float* dst = part + g2 * FCO;
        #pragma unroll
        for (int f = 0; f < FCO; ++f) dst[f] = o[f];
    }
}

// ---------------- K4: per-pixel aggregation ----------------
__global__ __launch_bounds__(256)
void agg_kernel(const float* __restrict__ x, const int* __restrict__ nbr,
                const float* __restrict__ Wl, const float* __restrict__ bl,
                const float* __restrict__ eg, const float* __restrict__ m0v,
                const float* __restrict__ part, float* __restrict__ out) {
    __shared__ int   spj[KNB];
    __shared__ int   sval[KNB];
    __shared__ float sE[FCO];
    __shared__ float sS[KNB][FCO];
    __shared__ float sxv[2][CIN][KNB];
    __shared__ float sT[2][CIN][FCO];
    __shared__ float spp[256];

    const int p = blockIdx.x;
    const int t = threadIdx.x;

    if (t < KNB) {
        int idx = nbr[p * KNB + t];
        spj[t]  = max(idx, 0);
        sval[t] = (idx >= 0) ? 1 : 0;
    } else if (t >= 32 && t < 32 + FCO) {
        int f = t - 32;
        sE[f] = eg[(p * 6 + 0) * FCO + f] + eg[(p * 6 + 1) * FCO + f]
              + eg[(p * 6 + 2) * FCO + f] + m0v[f];
    }
    __syncthreads();

    for (int e = t; e < 2 * CIN * KNB; e += 256) {
        int bb = e / (CIN * KNB);
        int r  = e - bb * (CIN * KNB);
        int c  = r / KNB;
        int j  = r - c * KNB;
        sxv[bb][c][j] = x[bb * (CIN * NPIX) + c * NPIX + spj[j]];
    }
    for (int idx = t; idx < KNB * FCO; idx += 256) {
        int j = idx >> 4, f = idx & 15;
        float acc = part[(p * KNB + j) * FCO + f];
        int n6 = spj[j] * 6;
        acc += eg[(n6 + 3) * FCO + f] + eg[(n6 + 4) * FCO + f] + eg[(n6 + 5) * FCO + f];
        acc += sE[f];
        sS[j][f] = sval[j] ? acc * 0.25f : 0.f;
    }
    __syncthreads();

    for (int tt = t; tt < 2 * CIN * FCO; tt += 256) {
        int bb = tt >> 9;
        int c  = (tt >> 4) & 31;
        int f  = tt & 15;
        float acc = 0.f;
        #pragma unroll
        for (int j = 0; j < KNB; ++j)
            acc += sxv[bb][c][j] * sS[j][f];
        sT[bb][c][f] = acc;
    }
    __syncthreads();

    {
        int half = t >> 7, q = t & 127, bb = q >> 6, co = q & 63;
        const float* Tb = &sT[bb][0][0];
        float acc = 0.f;
        int cf0 = half * 256;
        #pragma unroll 8
        for (int cf = cf0; cf < cf0 + 256; ++cf)
            acc += Tb[cf] * Wl[cf * COUT + co];
        spp[t] = acc;
    }
    __syncthreads();
    if (t < 128) {
        int bb = t >> 6, co = t & 63;
        out[bb * (COUT * NPIX) + co * NPIX + p] = spp[t] + spp[t + 128] + bl[co];
    }
}

extern "C" void kernel_launch(void* const* d_in, const int* in_sizes, int n_in,
                              void* d_out, int out_size, void* d_ws, size_t ws_size,
                              hipStream_t stream) {
    const float* x  = (const float*)d_in[0];
    const int* nbr  = (const int*)d_in[1];
    const float* W1 = (const float*)d_in[2];
    const float* b1 = (const float*)d_in[3];
    const float* W2 = (const float*)d_in[4];
    const float* b2 = (const float*)d_in[5];
    const float* W3 = (const float*)d_in[6];
    const float* b3 = (const float*)d_in[7];
    const float* Wl = (const float*)d_in[8];
    const float* bl = (const float*)d_in[9];
    float* out = (float*)d_out;

    char* ws = (char*)d_ws;
    double* rp64 = (double*)(ws + WS_RP64);
    float*  eg   = (float*)(ws + WS_EG);
    float*  m0v  = (float*)(ws + WS_M0);
    float*  vws  = (float*)(ws + WS_V);
    float*  part = (float*)(ws + WS_PART);

    hipLaunchKernelGGL(rp_kernel, dim3((NPIX + 255) / 256), dim3(256), 0, stream,
                       rp64);
    hipLaunchKernelGGL(edge_kernel, dim3((NPIX * 6 + 1 + 255) / 256), dim3(256), 0, stream,
                       W1, b1, W2, b2, W3, b3, rp64, eg, m0v);
    hipLaunchKernelGGL(vlog_kernel, dim3((NPJ + 255) / 256), dim3(256), 0, stream,
                       nbr, rp64, vws);
    int waves = (NPJ + 6) / 7;                  // 9546
    int blocks = (waves + 3) / 4;               // 2387
    hipLaunchKernelGGL(mlp1_kernel, dim3(blocks), dim3(256), 0, stream,
                       W1, b1, W2, b2, W3, b3, vws, part);
    hipLaunchKernelGGL(agg_kernel, dim3(NPIX), dim3(256), 0, stream,
                       x, nbr, Wl, bl, eg, m0v, part, out);
}

// Round 10
// 87.473 us; speedup vs baseline: 1.0701x; 1.0701x over previous
//
#include <hip/hip_runtime.h>

#define WW   48
#define NPIX 2304
#define CIN  32
#define COUT 64
#define KNB  29
#define FCO  16
#define NPJ  (NPIX * KNB)                      // 66816 (p,j) pairs
#define GEN_WAVES  ((NPJ + 6) / 7)             // 9546
#define GEN_BLOCKS ((GEN_WAVES + 3) / 4)       // 2387
#define EDGE_BLOCKS ((NPIX * 6 + 1 + 255) / 256)  // 55

// workspace layout (bytes); total 5,326,912
#define WS_RP64 0                // 2304*9*8    = 165888   f64 Rp
#define WS_EG   165888           // 2304*6*16*4 = 884736   edge MLP outs
#define WS_M0   1050624          // 16*4        = 64       MLP(0)
#define WS_PART 1050688          // 66816*16*4  = 4276224  per-(p,j) 9-eval sums

__device__ __forceinline__ float swish_f(float x) {
    return x * __builtin_amdgcn_rcpf(1.0f + __expf(-x));
}

// f64 Rodrigues matching reference so3_exp
__device__ __forceinline__ void so3_exp_d(double wx, double wy, double wz, double R[9]) {
    double n  = sqrt(wx * wx + wy * wy + wz * wz);
    double th = fmax(n, 1e-7);
    double kx = wx / th, ky = wy / th, kz = wz / th;
    double s = sin(th), c = cos(th);
    double omc = 1.0 - c;
    R[0] = 1.0 + omc * (kx * kx - 1.0);
    R[1] = -s * kz + omc * kx * ky;
    R[2] =  s * ky + omc * kx * kz;
    R[3] =  s * kz + omc * kx * ky;
    R[4] = 1.0 + omc * (ky * ky - 1.0);
    R[5] = -s * kx + omc * ky * kz;
    R[6] = -s * ky + omc * kz * kx;
    R[7] =  s * kx + omc * kz * ky;
    R[8] = 1.0 + omc * (kz * kz - 1.0);
}

// f64 fisheye lift rotation Rp for pixel p (matches reference _lift_log)
__device__ __forceinline__ void compute_Rp_d(int p, double R[9]) {
    int ui = p % WW, vi = p / WW;
    double dx = (double)ui - 23.5;
    double dy = (double)vi - 23.5;
    double r  = sqrt(dx * dx + dy * dy);
    const double FOCAL = 48.0 / 3.14159265358979323846;
    double theta = r / FOCAL;
    double rs = fmax(r, 1e-7);
    double st = sin(theta);
    double rayx = st * dx / rs;
    double rayy = st * dy / rs;
    double rayz = cos(theta);
    double pz  = fmin(fmax(rayz, -1.0 + 1e-6), 1.0 - 1e-6);
    double ang = acos(pz);
    double ax = -rayy, ay = rayx;
    double an = fmax(sqrt(ax * ax + ay * ay), 1e-7);
    ax /= an; ay /= an;
    so3_exp_d(ax * ang, ay * ang, 0.0, R);
}

// One 16-column half of layer2 + its layer3 fold (scalar, round-8 proven form).
// Recomputes h1 to keep peak live ~44 VGPRs -> no AGPR shuffle, no scratch.
__device__ __forceinline__ void mlp_half(float ab0, float ab1, float ab2, const int Q0,
    const float* __restrict__ W1, const float* __restrict__ b1,
    const float* __restrict__ W2, const float* __restrict__ b2,
    const float* __restrict__ W3, const float* __restrict__ b3,
    float* acc3) {
    float accq[16];
    #pragma unroll
    for (int q = 0; q < 16; ++q) accq[q] = b2[Q0 + q];
    #pragma unroll
    for (int i = 0; i < 32; ++i) {
        float h = swish_f(b1[i] + ab0 * W1[i] + ab1 * W1[32 + i] + ab2 * W1[64 + i]);
        #pragma unroll
        for (int q = 0; q < 16; ++q) accq[q] += h * W2[i * 32 + Q0 + q];
    }
    #pragma unroll
    for (int q = 0; q < 16; ++q) {
        float h2 = swish_f(accq[q]);
        #pragma unroll
        for (int f = 0; f < FCO; ++f) acc3[f] += h2 * W3[(Q0 + q) * FCO + f];
    }
}

// streaming f32 MLP 3->32->32->16 in two low-pressure passes
__device__ __forceinline__ void mlp_eval(float ab0, float ab1, float ab2,
    const float* __restrict__ W1, const float* __restrict__ b1,
    const float* __restrict__ W2, const float* __restrict__ b2,
    const float* __restrict__ W3, const float* __restrict__ b3,
    float* o) {
    float acc3[FCO];
    #pragma unroll
    for (int f = 0; f < FCO; ++f) acc3[f] = b3[f];
    mlp_half(ab0, ab1, ab2, 0,  W1, b1, W2, b2, W3, b3, acc3);
    __builtin_amdgcn_sched_barrier(0);   // keep the two passes' pressure isolated
    mlp_half(ab0, ab1, ab2, 16, W1, b1, W2, b2, W3, b3, acc3);
    #pragma unroll
    for (int f = 0; f < FCO; ++f) o[f] = swish_f(acc3[f]);
}

// ---------------- K0: per-pixel f64 lift rotation ----------------
__global__ __launch_bounds__(256)
void rp_kernel(double* __restrict__ rp64) {
    int p = blockIdx.x * 256 + threadIdx.x;
    if (p >= NPIX) return;
    double R[9];
    compute_Rp_d(p, R);
    #pragma unroll
    for (int e = 0; e < 9; ++e) rp64[p * 9 + e] = R[e];
}

// ---------------- K1 (fused): generic evals + inline vlog | edge evals ----------------
// Blocks [0, GEN_BLOCKS): 7 (p,j) pairs per wave, 9 lanes each (lane 63 idle).
// Each lane computes its OWN v_d inline: X = Rn^T*Rq (f64, streamed), one log.
// Blocks [GEN_BLOCKS, GEN_BLOCKS+EDGE_BLOCKS): per-pixel edge MLP evals -> eg/m0v.
__global__ __launch_bounds__(256)
void fused_kernel(const int* __restrict__ nbr,
                  const float* __restrict__ W1, const float* __restrict__ b1,
                  const float* __restrict__ W2, const float* __restrict__ b2,
                  const float* __restrict__ W3, const float* __restrict__ b3,
                  const double* __restrict__ rp64,
                  float* __restrict__ eg, float* __restrict__ m0v,
                  float* __restrict__ part) {
    if (blockIdx.x < GEN_BLOCKS) {
        int wave = blockIdx.x * 4 + (threadIdx.x >> 6);
        int lane = threadIdx.x & 63;
        int slot = lane / 9;              // 0..7 (slot 7 = lane 63, never writes)
        int e    = lane - slot * 9;       // 0..8
        int g2   = wave * 7 + slot;
        int g2c  = min(g2, NPJ - 1);
        int p = g2c / KNB, j = g2c - p * KNB;
        int pj = max(nbr[p * KNB + j], 0);
        int l1m = e / 3, l2m = e - l1m * 3;
        int l1 = l1m + (l1m >> 1);        // 0,1,3
        int l2 = l2m + (l2m >> 1);
        int d  = (l1 - l2) & 3;
        // X = Rn^T * Rq (f64), Rn streamed row-wise to bound pressure
        double Rq[9];
        #pragma unroll
        for (int q = 0; q < 9; ++q) Rq[q] = rp64[p * 9 + q];
        double X[9];
        #pragma unroll
        for (int q = 0; q < 9; ++q) X[q] = 0.0;
        #pragma unroll
        for (int k = 0; k < 3; ++k) {
            double rn0 = rp64[pj * 9 + k * 3 + 0];
            double rn1 = rp64[pj * 9 + k * 3 + 1];
            double rn2 = rp64[pj * 9 + k * 3 + 2];
            #pragma unroll
            for (int jj = 0; jj < 3; ++jj) {
                X[0 * 3 + jj] += rn0 * Rq[k * 3 + jj];
                X[1 * 3 + jj] += rn1 * Rq[k * 3 + jj];
                X[2 * 3 + jj] += rn2 * Rq[k * 3 + jj];
            }
        }
        // M = X * Rz(d) (col mix, exact 90-deg), then so3_log (f64, ref clipping)
        double c = (d == 0) ? 1.0 : ((d == 2) ? -1.0 : 0.0);
        double s = (d == 1) ? 1.0 : ((d == 3) ? -1.0 : 0.0);
        double M0 =  X[0] * c + X[1] * s;
        double M1 = -X[0] * s + X[1] * c;
        double M2 =  X[2];
        double M3 =  X[3] * c + X[4] * s;
        double M4 = -X[3] * s + X[4] * c;
        double M5 =  X[5];
        double M6 =  X[6] * c + X[7] * s;
        double M7 = -X[6] * s + X[7] * c;
        double M8 =  X[8];
        double tr   = M0 + M4 + M8;
        double cosv = fmin(fmax((tr - 1.0) * 0.5, -1.0 + 1e-6), 1.0 - 1e-6);
        double th   = acos(cosv);
        double svv  = sqrt((1.0 - cosv) * (1.0 + cosv));
        double fac  = th / (2.0 * svv);
        float v0 = (float)((M7 - M5) * fac);
        float v1 = (float)((M2 - M6) * fac);
        float v2 = (float)((M3 - M1) * fac);
        // ab = Rz(-alpha_{l2}) * v  (branchless)
        float ab0 = (l2m == 0) ? v0 : ((l2m == 1) ?  v1 : -v1);
        float ab1 = (l2m == 0) ? v1 : ((l2m == 1) ? -v0 :  v0);
        __builtin_amdgcn_sched_barrier(0);   // f64 prep regs die here
        float o[FCO];
        mlp_eval(ab0, ab1, v2, W1, b1, W2, b2, W3, b3, o);
        // 9-lane reduction: offsets (1,2) then (3,6)
        #pragma unroll
        for (int f = 0; f < FCO; ++f) {
            float a = o[f];
            a += __shfl(a, min(lane + 1, 63)) + __shfl(a, min(lane + 2, 63));
            a += __shfl(a, min(lane + 3, 63)) + __shfl(a, min(lane + 6, 63));
            o[f] = a;
        }
        if (e == 0 && lane < 63 && g2 < NPJ) {
            float* dst = part + g2 * FCO;
            #pragma unroll
            for (int f = 0; f < FCO; ++f) dst[f] = o[f];
        }
    } else {
        // ---- edge path: per-pixel MLP(+-a[p,l]) and MLP(0) ----
        int g = (blockIdx.x - GEN_BLOCKS) * 256 + threadIdx.x;
        if (g > NPIX * 6) return;
        if (g == NPIX * 6) {
            float o[FCO];
            mlp_eval(0.f, 0.f, 0.f, W1, b1, W2, b2, W3, b3, o);
            #pragma unroll
            for (int f = 0; f < FCO; ++f) m0v[f] = o[f];
            return;
        }
        int pix = g / 6, which = g - pix * 6;
        double R[9];
        #pragma unroll
        for (int q = 0; q < 9; ++q) R[q] = rp64[pix * 9 + q];
        int m = (which < 3) ? which : (which - 3);
        int l = m + (m >> 1);                       // 0,1,3
        double c = (l == 0) ? 1.0 : 0.0;
        double s = (l == 1) ? 1.0 : ((l == 3) ? -1.0 : 0.0);
        double M[9];
        #pragma unroll
        for (int i = 0; i < 3; ++i) {
            M[i * 3 + 0] =  R[i * 3 + 0] * c + R[i * 3 + 1] * s;
            M[i * 3 + 1] = -R[i * 3 + 0] * s + R[i * 3 + 1] * c;
            M[i * 3 + 2] =  R[i * 3 + 2];
        }
        double tr   = M[0] + M[4] + M[8];
        double cosv = fmin(fmax((tr - 1.0) * 0.5, -1.0 + 1e-6), 1.0 - 1e-6);
        double th   = acos(cosv);
        double sv   = sqrt((1.0 - cosv) * (1.0 + cosv));
        double fac  = th / (2.0 * sv);
        float sg = (which < 3) ? 1.f : -1.f;
        float o[FCO];
        mlp_eval(sg * (float)((M[7] - M[5]) * fac),
                 sg * (float)((M[2] - M[6]) * fac),
                 sg * (float)((M[3] - M[1]) * fac),
                 W1, b1, W2, b2, W3, b3, o);
        #pragma unroll
        for (int f = 0; f < FCO; ++f) eg[g * FCO + f] = o[f];
    }
}

// ---------------- K2: per-pixel aggregation ----------------
__global__ __launch_bounds__(256)
void agg_kernel(const float* __restrict__ x, const int* __restrict__ nbr,
                const float* __restrict__ Wl, const float* __restrict__ bl,
                const float* __restrict__ eg, const float* __restrict__ m0v,
                const float* __restrict__ part, float* __restrict__ out) {
    __shared__ int   spj[KNB];
    __shared__ int   sval[KNB];
    __shared__ float sE[FCO];
    __shared__ float sS[KNB][FCO];
    __shared__ float sxv[2][CIN][KNB];
    __shared__ float sT[2][CIN][FCO];
    __shared__ float spp[256];

    const int p = blockIdx.x;
    const int t = threadIdx.x;

    if (t < KNB) {
        int idx = nbr[p * KNB + t];
        spj[t]  = max(idx, 0);
        sval[t] = (idx >= 0) ? 1 : 0;
    } else if (t >= 32 && t < 32 + FCO) {
        int f = t - 32;
        sE[f] = eg[(p * 6 + 0) * FCO + f] + eg[(p * 6 + 1) * FCO + f]
              + eg[(p * 6 + 2) * FCO + f] + m0v[f];
    }
    __syncthreads();

    for (int e = t; e < 2 * CIN * KNB; e += 256) {
        int bb = e / (CIN * KNB);
        int r  = e - bb * (CIN * KNB);
        int c  = r / KNB;
        int j  = r - c * KNB;
        sxv[bb][c][j] = x[bb * (CIN * NPIX) + c * NPIX + spj[j]];
    }
    for (int idx = t; idx < KNB * FCO; idx += 256) {
        int j = idx >> 4, f = idx & 15;
        float acc = part[(p * KNB + j) * FCO + f];
        int n6 = spj[j] * 6;
        acc += eg[(n6 + 3) * FCO + f] + eg[(n6 + 4) * FCO + f] + eg[(n6 + 5) * FCO + f];
        acc += sE[f];
        sS[j][f] = sval[j] ? acc * 0.25f : 0.f;
    }
    __syncthreads();

    for (int tt = t; tt < 2 * CIN * FCO; tt += 256) {
        int bb = tt >> 9;
        int c  = (tt >> 4) & 31;
        int f  = tt & 15;
        float acc = 0.f;
        #pragma unroll
        for (int j = 0; j < KNB; ++j)
            acc += sxv[bb][c][j] * sS[j][f];
        sT[bb][c][f] = acc;
    }
    __syncthreads();

    {
        int half = t >> 7, q = t & 127, bb = q >> 6, co = q & 63;
        const float* Tb = &sT[bb][0][0];
        float acc = 0.f;
        int cf0 = half * 256;
        #pragma unroll 8
        for (int cf = cf0; cf < cf0 + 256; ++cf)
            acc += Tb[cf] * Wl[cf * COUT + co];
        spp[t] = acc;
    }
    __syncthreads();
    if (t < 128) {
        int bb = t >> 6, co = t & 63;
        out[bb * (COUT * NPIX) + co * NPIX + p] = spp[t] + spp[t + 128] + bl[co];
    }
}

extern "C" void kernel_launch(void* const* d_in, const int* in_sizes, int n_in,
                              void* d_out, int out_size, void* d_ws, size_t ws_size,
                              hipStream_t stream) {
    const float* x  = (const float*)d_in[0];
    const int* nbr  = (const int*)d_in[1];
    const float* W1 = (const float*)d_in[2];
    const float* b1 = (const float*)d_in[3];
    const float* W2 = (const float*)d_in[4];
    const float* b2 = (const float*)d_in[5];
    const float* W3 = (const float*)d_in[6];
    const float* b3 = (const float*)d_in[7];
    const float* Wl = (const float*)d_in[8];
    const float* bl = (const float*)d_in[9];
    float* out = (float*)d_out;

    char* ws = (char*)d_ws;
    double* rp64 = (double*)(ws + WS_RP64);
    float*  eg   = (float*)(ws + WS_EG);
    float*  m0v  = (float*)(ws + WS_M0);
    float*  part = (float*)(ws + WS_PART);

    hipLaunchKernelGGL(rp_kernel, dim3((NPIX + 255) / 256), dim3(256), 0, stream,
                       rp64);
    hipLaunchKernelGGL(fused_kernel, dim3(GEN_BLOCKS + EDGE_BLOCKS), dim3(256), 0, stream,
                       nbr, W1, b1, W2, b2, W3, b3, rp64, eg, m0v, part);
    hipLaunchKernelGGL(agg_kernel, dim3(NPIX), dim3(256), 0, stream,
                       x, nbr, Wl, bl, eg, m0v, part, out);
}

// Round 11
// 84.719 us; speedup vs baseline: 1.1049x; 1.0325x over previous
//
#include <hip/hip_runtime.h>

#define WW   48
#define NPIX 2304
#define CIN  32
#define COUT 64
#define KNB  29
#define FCO  16
#define NPJ  (NPIX * KNB)                      // 66816 (p,j) pairs
#define GEN_WAVES  ((NPJ + 6) / 7)             // 9546
#define GEN_BLOCKS ((GEN_WAVES + 3) / 4)       // 2387
#define EDGE_BLOCKS ((NPIX * 6 + 1 + 255) / 256)  // 55

// workspace layout (bytes); total 5,326,912
#define WS_RP64 0                // 2304*9*8    = 165888   f64 Rp
#define WS_EG   165888           // 2304*6*16*4 = 884736   edge MLP outs
#define WS_M0   1050624          // 16*4        = 64       MLP(0)
#define WS_PART 1050688          // 66816*16*4  = 4276224  per-(p,j) 9-eval sums

__device__ __forceinline__ float swish_f(float x) {
    return x * __builtin_amdgcn_rcpf(1.0f + __expf(-x));
}

// f64 Rodrigues matching reference so3_exp
__device__ __forceinline__ void so3_exp_d(double wx, double wy, double wz, double R[9]) {
    double n  = sqrt(wx * wx + wy * wy + wz * wz);
    double th = fmax(n, 1e-7);
    double kx = wx / th, ky = wy / th, kz = wz / th;
    double s = sin(th), c = cos(th);
    double omc = 1.0 - c;
    R[0] = 1.0 + omc * (kx * kx - 1.0);
    R[1] = -s * kz + omc * kx * ky;
    R[2] =  s * ky + omc * kx * kz;
    R[3] =  s * kz + omc * kx * ky;
    R[4] = 1.0 + omc * (ky * ky - 1.0);
    R[5] = -s * kx + omc * ky * kz;
    R[6] = -s * ky + omc * kz * kx;
    R[7] =  s * kx + omc * kz * ky;
    R[8] = 1.0 + omc * (kz * kz - 1.0);
}

// f64 fisheye lift rotation Rp for pixel p (matches reference _lift_log)
__device__ __forceinline__ void compute_Rp_d(int p, double R[9]) {
    int ui = p % WW, vi = p / WW;
    double dx = (double)ui - 23.5;
    double dy = (double)vi - 23.5;
    double r  = sqrt(dx * dx + dy * dy);
    const double FOCAL = 48.0 / 3.14159265358979323846;
    double theta = r / FOCAL;
    double rs = fmax(r, 1e-7);
    double st = sin(theta);
    double rayx = st * dx / rs;
    double rayy = st * dy / rs;
    double rayz = cos(theta);
    double pz  = fmin(fmax(rayz, -1.0 + 1e-6), 1.0 - 1e-6);
    double ang = acos(pz);
    double ax = -rayy, ay = rayx;
    double an = fmax(sqrt(ax * ax + ay * ay), 1e-7);
    ax /= an; ay /= an;
    so3_exp_d(ax * ang, ay * ang, 0.0, R);
}

// Full-width streaming f32 MLP 3->32->32->16, single pass.
// Per-element accumulation order identical to the previous half-split
// version (q<16 then q>=16 fold in same order) -> bit-identical output.
__device__ __forceinline__ void mlp_eval(float ab0, float ab1, float ab2,
    const float* __restrict__ W1, const float* __restrict__ b1,
    const float* __restrict__ W2, const float* __restrict__ b2,
    const float* __restrict__ W3, const float* __restrict__ b3,
    float* o) {
    float acc2[32];
    #pragma unroll
    for (int q = 0; q < 32; ++q) acc2[q] = b2[q];
    #pragma unroll
    for (int i = 0; i < 32; ++i) {
        float h = swish_f(b1[i] + ab0 * W1[i] + ab1 * W1[32 + i] + ab2 * W1[64 + i]);
        #pragma unroll
        for (int q = 0; q < 32; ++q) acc2[q] += h * W2[i * 32 + q];
    }
    float acc3[FCO];
    #pragma unroll
    for (int f = 0; f < FCO; ++f) acc3[f] = b3[f];
    #pragma unroll
    for (int q = 0; q < 32; ++q) {
        float h2 = swish_f(acc2[q]);
        #pragma unroll
        for (int f = 0; f < FCO; ++f) acc3[f] += h2 * W3[q * FCO + f];
    }
    #pragma unroll
    for (int f = 0; f < FCO; ++f) o[f] = swish_f(acc3[f]);
}

// ---------------- K0: per-pixel f64 lift rotation ----------------
__global__ __launch_bounds__(256)
void rp_kernel(double* __restrict__ rp64) {
    int p = blockIdx.x * 256 + threadIdx.x;
    if (p >= NPIX) return;
    double R[9];
    compute_Rp_d(p, R);
    #pragma unroll
    for (int e = 0; e < 9; ++e) rp64[p * 9 + e] = R[e];
}

// ---------------- K1 (fused): generic evals + inline vlog | edge evals ----------------
// waves_per_eu(6,7): cap at 6-7 waves/SIMD -> ~85 VGPR budget. This is the
// anti-squeeze knob: stops the allocator from targeting 8 waves and parking
// acc2[32] in AGPRs (3x issue on the hot loop, round-7 pathology).
__global__ __launch_bounds__(256)
__attribute__((amdgpu_waves_per_eu(6, 7)))
void fused_kernel(const int* __restrict__ nbr,
                  const float* __restrict__ W1, const float* __restrict__ b1,
                  const float* __restrict__ W2, const float* __restrict__ b2,
                  const float* __restrict__ W3, const float* __restrict__ b3,
                  const double* __restrict__ rp64,
                  float* __restrict__ eg, float* __restrict__ m0v,
                  float* __restrict__ part) {
    if (blockIdx.x < GEN_BLOCKS) {
        int wave = blockIdx.x * 4 + (threadIdx.x >> 6);
        int lane = threadIdx.x & 63;
        int slot = lane / 9;              // 0..7 (slot 7 = lane 63, never writes)
        int e    = lane - slot * 9;       // 0..8
        int g2   = wave * 7 + slot;
        int g2c  = min(g2, NPJ - 1);
        int p = g2c / KNB, j = g2c - p * KNB;
        int pj = max(nbr[p * KNB + j], 0);
        int l1m = e / 3, l2m = e - l1m * 3;
        int l1 = l1m + (l1m >> 1);        // 0,1,3
        int l2 = l2m + (l2m >> 1);
        int d  = (l1 - l2) & 3;
        // X = Rn^T * Rq (f64), Rn streamed row-wise to bound pressure
        double Rq[9];
        #pragma unroll
        for (int q = 0; q < 9; ++q) Rq[q] = rp64[p * 9 + q];
        double X[9];
        #pragma unroll
        for (int q = 0; q < 9; ++q) X[q] = 0.0;
        #pragma unroll
        for (int k = 0; k < 3; ++k) {
            double rn0 = rp64[pj * 9 + k * 3 + 0];
            double rn1 = rp64[pj * 9 + k * 3 + 1];
            double rn2 = rp64[pj * 9 + k * 3 + 2];
            #pragma unroll
            for (int jj = 0; jj < 3; ++jj) {
                X[0 * 3 + jj] += rn0 * Rq[k * 3 + jj];
                X[1 * 3 + jj] += rn1 * Rq[k * 3 + jj];
                X[2 * 3 + jj] += rn2 * Rq[k * 3 + jj];
            }
        }
        // M = X * Rz(d) (col mix, exact 90-deg), then so3_log (f64, ref clipping)
        double c = (d == 0) ? 1.0 : ((d == 2) ? -1.0 : 0.0);
        double s = (d == 1) ? 1.0 : ((d == 3) ? -1.0 : 0.0);
        double M0 =  X[0] * c + X[1] * s;
        double M1 = -X[0] * s + X[1] * c;
        double M2 =  X[2];
        double M3 =  X[3] * c + X[4] * s;
        double M4 = -X[3] * s + X[4] * c;
        double M5 =  X[5];
        double M6 =  X[6] * c + X[7] * s;
        double M7 = -X[6] * s + X[7] * c;
        double M8 =  X[8];
        double tr   = M0 + M4 + M8;
        double cosv = fmin(fmax((tr - 1.0) * 0.5, -1.0 + 1e-6), 1.0 - 1e-6);
        double th   = acos(cosv);
        double svv  = sqrt((1.0 - cosv) * (1.0 + cosv));
        double fac  = th / (2.0 * svv);
        float v0 = (float)((M7 - M5) * fac);
        float v1 = (float)((M2 - M6) * fac);
        float v2 = (float)((M3 - M1) * fac);
        // ab = Rz(-alpha_{l2}) * v  (branchless)
        float ab0 = (l2m == 0) ? v0 : ((l2m == 1) ?  v1 : -v1);
        float ab1 = (l2m == 0) ? v1 : ((l2m == 1) ? -v0 :  v0);
        __builtin_amdgcn_sched_barrier(0);   // f64 prep regs die here
        float o[FCO];
        mlp_eval(ab0, ab1, v2, W1, b1, W2, b2, W3, b3, o);
        // 9-lane reduction: offsets (1,2) then (3,6)
        #pragma unroll
        for (int f = 0; f < FCO; ++f) {
            float a = o[f];
            a += __shfl(a, min(lane + 1, 63)) + __shfl(a, min(lane + 2, 63));
            a += __shfl(a, min(lane + 3, 63)) + __shfl(a, min(lane + 6, 63));
            o[f] = a;
        }
        if (e == 0 && lane < 63 && g2 < NPJ) {
            float* dst = part + g2 * FCO;
            #pragma unroll
            for (int f = 0; f < FCO; ++f) dst[f] = o[f];
        }
    } else {
        // ---- edge path: per-pixel MLP(+-a[p,l]) and MLP(0) ----
        int g = (blockIdx.x - GEN_BLOCKS) * 256 + threadIdx.x;
        if (g > NPIX * 6) return;
        if (g == NPIX * 6) {
            float o[FCO];
            mlp_eval(0.f, 0.f, 0.f, W1, b1, W2, b2, W3, b3, o);
            #pragma unroll
            for (int f = 0; f < FCO; ++f) m0v[f] = o[f];
            return;
        }
        int pix = g / 6, which = g - pix * 6;
        double R[9];
        #pragma unroll
        for (int q = 0; q < 9; ++q) R[q] = rp64[pix * 9 + q];
        int m = (which < 3) ? which : (which - 3);
        int l = m + (m >> 1);                       // 0,1,3
        double c = (l == 0) ? 1.0 : 0.0;
        double s = (l == 1) ? 1.0 : ((l == 3) ? -1.0 : 0.0);
        double M[9];
        #pragma unroll
        for (int i = 0; i < 3; ++i) {
            M[i * 3 + 0] =  R[i * 3 + 0] * c + R[i * 3 + 1] * s;
            M[i * 3 + 1] = -R[i * 3 + 0] * s + R[i * 3 + 1] * c;
            M[i * 3 + 2] =  R[i * 3 + 2];
        }
        double tr   = M[0] + M[4] + M[8];
        double cosv = fmin(fmax((tr - 1.0) * 0.5, -1.0 + 1e-6), 1.0 - 1e-6);
        double th   = acos(cosv);
        double sv   = sqrt((1.0 - cosv) * (1.0 + cosv));
        double fac  = th / (2.0 * sv);
        float sg = (which < 3) ? 1.f : -1.f;
        float o[FCO];
        mlp_eval(sg * (float)((M[7] - M[5]) * fac),
                 sg * (float)((M[2] - M[6]) * fac),
                 sg * (float)((M[3] - M[1]) * fac),
                 W1, b1, W2, b2, W3, b3, o);
        #pragma unroll
        for (int f = 0; f < FCO; ++f) eg[g * FCO + f] = o[f];
    }
}

// ---------------- K2: per-pixel aggregation ----------------
__global__ __launch_bounds__(256)
void agg_kernel(const float* __restrict__ x, const int* __restrict__ nbr,
                const float* __restrict__ Wl, const float* __restrict__ bl,
                const float* __restrict__ eg, const float* __restrict__ m0v,
                const float* __restrict__ part, float* __restrict__ out) {
    __shared__ int   spj[KNB];
    __shared__ int   sval[KNB];
    __shared__ float sE[FCO];
    __shared__ float sS[KNB][FCO];
    __shared__ float sxv[2][CIN][KNB];
    __shared__ float sT[2][CIN][FCO];
    __shared__ float spp[256];

    const int p = blockIdx.x;
    const int t = threadIdx.x;

    if (t < KNB) {
        int idx = nbr[p * KNB + t];
        spj[t]  = max(idx, 0);
        sval[t] = (idx >= 0) ? 1 : 0;
    } else if (t >= 32 && t < 32 + FCO) {
        int f = t - 32;
        sE[f] = eg[(p * 6 + 0) * FCO + f] + eg[(p * 6 + 1) * FCO + f]
              + eg[(p * 6 + 2) * FCO + f] + m0v[f];
    }
    __syncthreads();

    for (int e = t; e < 2 * CIN * KNB; e += 256) {
        int bb = e / (CIN * KNB);
        int r  = e - bb * (CIN * KNB);
        int c  = r / KNB;
        int j  = r - c * KNB;
        sxv[bb][c][j] = x[bb * (CIN * NPIX) + c * NPIX + spj[j]];
    }
    for (int idx = t; idx < KNB * FCO; idx += 256) {
        int j = idx >> 4, f = idx & 15;
        float acc = part[(p * KNB + j) * FCO + f];
        int n6 = spj[j] * 6;
        acc += eg[(n6 + 3) * FCO + f] + eg[(n6 + 4) * FCO + f] + eg[(n6 + 5) * FCO + f];
        acc += sE[f];
        sS[j][f] = sval[j] ? acc * 0.25f : 0.f;
    }
    __syncthreads();

    for (int tt = t; tt < 2 * CIN * FCO; tt += 256) {
        int bb = tt >> 9;
        int c  = (tt >> 4) & 31;
        int f  = tt & 15;
        float acc = 0.f;
        #pragma unroll
        for (int j = 0; j < KNB; ++j)
            acc += sxv[bb][c][j] * sS[j][f];
        sT[bb][c][f] = acc;
    }
    __syncthreads();

    {
        int half = t >> 7, q = t & 127, bb = q >> 6, co = q & 63;
        const float* Tb = &sT[bb][0][0];
        float acc = 0.f;
        int cf0 = half * 256;
        #pragma unroll 8
        for (int cf = cf0; cf < cf0 + 256; ++cf)
            acc += Tb[cf] * Wl[cf * COUT + co];
        spp[t] = acc;
    }
    __syncthreads();
    if (t < 128) {
        int bb = t >> 6, co = t & 63;
        out[bb * (COUT * NPIX) + co * NPIX + p] = spp[t] + spp[t + 128] + bl[co];
    }
}

extern "C" void kernel_launch(void* const* d_in, const int* in_sizes, int n_in,
                              void* d_out, int out_size, void* d_ws, size_t ws_size,
                              hipStream_t stream) {
    const float* x  = (const float*)d_in[0];
    const int* nbr  = (const int*)d_in[1];
    const float* W1 = (const float*)d_in[2];
    const float* b1 = (const float*)d_in[3];
    const float* W2 = (const float*)d_in[4];
    const float* b2 = (const float*)d_in[5];
    const float* W3 = (const float*)d_in[6];
    const float* b3 = (const float*)d_in[7];
    const float* Wl = (const float*)d_in[8];
    const float* bl = (const float*)d_in[9];
    float* out = (float*)d_out;

    char* ws = (char*)d_ws;
    double* rp64 = (double*)(ws + WS_RP64);
    float*  eg   = (float*)(ws + WS_EG);
    float*  m0v  = (float*)(ws + WS_M0);
    float*  part = (float*)(ws + WS_PART);

    hipLaunchKernelGGL(rp_kernel, dim3((NPIX + 255) / 256), dim3(256), 0, stream,
                       rp64);
    hipLaunchKernelGGL(fused_kernel, dim3(GEN_BLOCKS + EDGE_BLOCKS), dim3(256), 0, stream,
                       nbr, W1, b1, W2, b2, W3, b3, rp64, eg, m0v, part);
    hipLaunchKernelGGL(agg_kernel, dim3(NPIX), dim3(256), 0, stream,
                       x, nbr, Wl, bl, eg, m0v, part, out);
}